// Round 12
// baseline (262.703 us; speedup 1.0000x reference)
//
#include <hip/hip_runtime.h>
#include <hip/hip_bf16.h>
#include <math.h>

#define B_   256
#define D1_  512
#define T_   256
#define O1_  256
#define O2_  128

typedef __attribute__((ext_vector_type(8))) _Float16 f16x8;
typedef __attribute__((ext_vector_type(4))) float f32x4;

#define E_BYTES  (33554432u)   // 256*256*256*2
#define WT_BYTES (131072u)     // 256*256*2

__device__ inline f16x8 cvt8h(const float* v) {
    f16x8 r;
    #pragma unroll
    for (int j = 0; j < 8; ++j) r[j] = (_Float16)v[j];
    return r;
}
__device__ inline f16x8 ld16(const char* p) {
    union { uint2 a[2]; f16x8 v; } f;
    f.a[0] = *(const uint2*)p;
    f.a[1] = *(const uint2*)(p + 8);
    return f.v;
}
__device__ inline f16x8 ldb128(const char* p) { return *(const f16x8*)p; }

#define MFMAH __builtin_amdgcn_mfma_f32_16x16x32_f16

// ===== K0: WT[s][t] = fp16(W[t][s]); W2T[s2][t] = fp16(W2[t][s2]) =====
__global__ __launch_bounds__(256) void prep_wt(
    const float* __restrict__ W, const float* __restrict__ W2,
    _Float16* __restrict__ WT, _Float16* __restrict__ W2T)
{
    int g = blockIdx.x * 256 + threadIdx.x;
    if (g < 65536) {
        int s = g >> 8, t = g & 255;
        WT[g] = (_Float16)W[t * 256 + s];
    } else {
        int h = g - 65536;
        int s2 = h >> 8, t = h & 255;
        W2T[h] = (_Float16)W2[t * 128 + s2];
    }
}

// ===== K1: E[b][o][t] = W1h @ (xh + xl), fp16 out. 128o x 64t tiles, =====
// 256 threads (4 waves 2m x 2n), transposed-LDS x staging, 1 barrier/chunk.
__global__ __launch_bounds__(256, 4) void k1_egemm(
    const float* __restrict__ x, const float* __restrict__ W1,
    _Float16* __restrict__ Eo)
{
    __shared__ __align__(16) char Bst[2][2][64 * 72];  // [buf][hi/lo][t*72]

    const int tid    = threadIdx.x;
    const int lane16 = tid & 15;
    const int lg     = (tid >> 4) & 3;
    const int wid    = tid >> 6;        // 0..3
    const int wm     = wid >> 1;        // 0..1
    const int wn     = wid & 1;         // 0..1

    // XCD grouping: 2048 blocks, 8 per batch; a batch's blocks share an XCD.
    const int bid = blockIdx.x;
    const int idx = bid >> 3;                 // 0..255
    const int b   = (bid & 7) + 8 * (idx >> 3);
    const int sub = idx & 7;                  // 0..7
    const int ob  = (sub >> 2) * 128;
    const int tb  = (sub & 3) * 64;

    const float* xb = x + (size_t)b * (D1_ * T_) + tb;
    const int st_t = tid & 63;          // staged t row
    const int st_k = tid >> 6;          // 0..3 -> k = st_k*8+j
    const int stO  = st_t * 72 + st_k * 16;

    int bOff[2];
    #pragma unroll
    for (int nt = 0; nt < 2; ++nt)
        bOff[nt] = (wn * 32 + nt * 16 + lane16) * 72 + lg * 16;

    f32x4 acc[4][2];
    #pragma unroll
    for (int mt = 0; mt < 4; ++mt)
        #pragma unroll
        for (int nt = 0; nt < 2; ++nt) acc[mt][nt] = (f32x4){0.f,0.f,0.f,0.f};

    // prologue: chunk 0 -> buf0
    {
        float xv[8];
        #pragma unroll
        for (int j = 0; j < 8; ++j) xv[j] = xb[(size_t)(st_k * 8 + j) * T_ + st_t];
        #pragma unroll
        for (int q = 0; q < 2; ++q) {
            uint2 hp, lp;
            _Float16 h0=(_Float16)xv[q*4+0], h1=(_Float16)xv[q*4+1];
            _Float16 h2=(_Float16)xv[q*4+2], h3=(_Float16)xv[q*4+3];
            union { _Float16 h[2]; unsigned u; } c0, c1;
            c0.h[0]=h0; c0.h[1]=h1; hp.x=c0.u; c1.h[0]=h2; c1.h[1]=h3; hp.y=c1.u;
            c0.h[0]=(_Float16)(xv[q*4+0]-(float)h0); c0.h[1]=(_Float16)(xv[q*4+1]-(float)h1); lp.x=c0.u;
            c1.h[0]=(_Float16)(xv[q*4+2]-(float)h2); c1.h[1]=(_Float16)(xv[q*4+3]-(float)h3); lp.y=c1.u;
            *(uint2*)(Bst[0][0] + stO + q * 8) = hp;
            *(uint2*)(Bst[0][1] + stO + q * 8) = lp;
        }
    }
    __syncthreads();

    for (int c = 0; c < 16; ++c) {
        const int cur = c & 1;
        // prefetch next x chunk into regs
        float xn[8];
        if (c < 15) {
            #pragma unroll
            for (int j = 0; j < 8; ++j)
                xn[j] = xb[(size_t)((c + 1) * 32 + st_k * 8 + j) * T_ + st_t];
        }
        // A fragments from global (W1 rows, k-contiguous), hi only
        f16x8 Ah[4];
        #pragma unroll
        for (int mt = 0; mt < 4; ++mt) {
            const float* ap = W1 + (size_t)(ob + wm * 64 + mt * 16 + lane16) * D1_ + c * 32 + lg * 8;
            float av[8];
            *(float4*)&av[0] = *(const float4*)ap;
            *(float4*)&av[4] = *(const float4*)(ap + 4);
            Ah[mt] = cvt8h(av);
        }
        // MFMA on staged buf
        __builtin_amdgcn_s_setprio(1);
        #pragma unroll
        for (int nt = 0; nt < 2; ++nt) {
            f16x8 Bh = ld16(Bst[cur][0] + bOff[nt]);
            f16x8 Bl = ld16(Bst[cur][1] + bOff[nt]);
            #pragma unroll
            for (int mt = 0; mt < 4; ++mt) {
                acc[mt][nt] = MFMAH(Ah[mt], Bh, acc[mt][nt], 0,0,0);
                acc[mt][nt] = MFMAH(Ah[mt], Bl, acc[mt][nt], 0,0,0);
            }
        }
        __builtin_amdgcn_s_setprio(0);
        // split+write next chunk
        if (c < 15) {
            #pragma unroll
            for (int q = 0; q < 2; ++q) {
                uint2 hp, lp;
                _Float16 h0=(_Float16)xn[q*4+0], h1=(_Float16)xn[q*4+1];
                _Float16 h2=(_Float16)xn[q*4+2], h3=(_Float16)xn[q*4+3];
                union { _Float16 h[2]; unsigned u; } c0, c1;
                c0.h[0]=h0; c0.h[1]=h1; hp.x=c0.u; c1.h[0]=h2; c1.h[1]=h3; hp.y=c1.u;
                c0.h[0]=(_Float16)(xn[q*4+0]-(float)h0); c0.h[1]=(_Float16)(xn[q*4+1]-(float)h1); lp.x=c0.u;
                c1.h[0]=(_Float16)(xn[q*4+2]-(float)h2); c1.h[1]=(_Float16)(xn[q*4+3]-(float)h3); lp.y=c1.u;
                *(uint2*)(Bst[cur^1][0] + stO + q * 8) = hp;
                *(uint2*)(Bst[cur^1][1] + stO + q * 8) = lp;
            }
        }
        __syncthreads();
    }

    // epilogue: store E fp16 (hi)
    #pragma unroll
    for (int mt = 0; mt < 4; ++mt)
        #pragma unroll
        for (int nt = 0; nt < 2; ++nt)
            #pragma unroll
            for (int i = 0; i < 4; ++i) {
                int o = ob + wm * 64 + mt * 16 + lg * 4 + i;
                int t = tb + wn * 32 + nt * 16 + lane16;
                Eo[((size_t)b * O1_ + o) * T_ + t] = (_Float16)acc[mt][nt][i];
            }
}

// ===== K2: S = E@WT -> row softmax (wave-local) -> blend -> Y = blended@W2T =====
// 64 o-rows per block, 256 threads (4 waves, each owns 16 complete rows).
__global__ __launch_bounds__(256, 4) void k2_sy(
    const _Float16* __restrict__ Eo, const _Float16* __restrict__ WT,
    const _Float16* __restrict__ W2T, const float* __restrict__ alpha,
    const float* __restrict__ bias, float* __restrict__ out)
{
    __shared__ __align__(16) char Eh[64 * 512];   // E / blended tile, XOR-swizzled

    const int tid    = threadIdx.x;
    const int lane   = tid & 63;
    const int lane16 = tid & 15;
    const int lg     = (tid >> 4) & 3;
    const int wid    = tid >> 6;     // 0..3: wave owns rows wid*16..+16

    // XCD grouping: 1024 blocks, 4 per batch.
    const int bid = blockIdx.x;
    const int idx = bid >> 3;                 // 0..127
    const int b   = (bid & 7) + 8 * (idx >> 2);
    const int ob  = (idx & 3) * 64;

    // copy-in: wave copies its 16 E rows (8 KB contiguous) ws -> LDS swizzled
    {
        const char* esrc = (const char*)(Eo + ((size_t)b * O1_ + ob + wid * 16) * T_);
        #pragma unroll
        for (int it = 0; it < 8; ++it) {
            int flat = it * 1024 + lane * 16;
            uint4 v = *(const uint4*)(esrc + flat);
            int r = wid * 16 + (flat >> 9);
            int inner = (flat & 511) ^ ((r & 7) << 4);
            *(uint4*)(Eh + r * 512 + inner) = v;
        }
    }
    __syncthreads();

    const int er = wid * 16 + lane16;
    const int eB = er * 512, eS = (er & 7) << 4;

    // stage 2: S[16 rows][256 s]
    f32x4 S[16];
    #pragma unroll
    for (int nt = 0; nt < 16; ++nt) S[nt] = (f32x4){0.f,0.f,0.f,0.f};
    for (int c = 0; c < 8; ++c) {
        f16x8 Af = ldb128(Eh + eB + ((c * 64 + lg * 16) ^ eS));
        #pragma unroll
        for (int nt = 0; nt < 16; ++nt) {
            f16x8 Bf = *(const f16x8*)((const char*)WT
                        + (size_t)(nt * 16 + lane16) * 512 + (c * 32 + lg * 8) * 2);
            S[nt] = MFMAH(Af, Bf, S[nt], 0,0,0);
        }
    }

    // wave-local row softmax + blend (rows fully owned by this wave)
    const float a_ = alpha[0];
    #pragma unroll
    for (int i = 0; i < 4; ++i) {
        float m = S[0][i];
        #pragma unroll
        for (int nt = 1; nt < 16; ++nt) m = fmaxf(m, S[nt][i]);
        m = fmaxf(m, __shfl_xor(m, 1));
        m = fmaxf(m, __shfl_xor(m, 2));
        m = fmaxf(m, __shfl_xor(m, 4));
        m = fmaxf(m, __shfl_xor(m, 8));
        float s = 0.f;
        #pragma unroll
        for (int nt = 0; nt < 16; ++nt) {
            float p = __expf(S[nt][i] - m);
            S[nt][i] = p; s += p;
        }
        s += __shfl_xor(s, 1);
        s += __shfl_xor(s, 2);
        s += __shfl_xor(s, 4);
        s += __shfl_xor(s, 8);
        float inv = 1.f / s;
        int r = wid * 16 + lg * 4 + i;
        #pragma unroll
        for (int nt = 0; nt < 16; ++nt) {
            int t = nt * 16 + lane16;
            int off = r * 512 + ((2 * t) ^ ((r & 7) << 4));
            union { _Float16 h; unsigned short u; } cc;
            cc.u = *(const unsigned short*)(Eh + off);
            float f = a_ + (1.f - a_) * S[nt][i] * inv;
            cc.h = (_Float16)((float)cc.h * f);
            *(unsigned short*)(Eh + off) = cc.u;
        }
    }
    __syncthreads();

    // stage 3: Y[16 rows][128 s2]
    f32x4 Y[8];
    #pragma unroll
    for (int nt = 0; nt < 8; ++nt) Y[nt] = (f32x4){0.f,0.f,0.f,0.f};
    for (int c = 0; c < 8; ++c) {
        f16x8 Af = ldb128(Eh + eB + ((c * 64 + lg * 16) ^ eS));
        #pragma unroll
        for (int nt = 0; nt < 8; ++nt) {
            f16x8 Bf = *(const f16x8*)((const char*)W2T
                        + (size_t)(nt * 16 + lane16) * 512 + (c * 32 + lg * 8) * 2);
            Y[nt] = MFMAH(Af, Bf, Y[nt], 0,0,0);
        }
    }

    // epilogue: + bias, store pre-softmax Y
    #pragma unroll
    for (int nt = 0; nt < 8; ++nt)
        #pragma unroll
        for (int i = 0; i < 4; ++i) {
            int o  = ob + wid * 16 + lg * 4 + i;
            int s2 = nt * 16 + lane16;
            out[((size_t)b * O1_ + o) * O2_ + s2] = Y[nt][i] + bias[(size_t)o * O2_ + s2];
        }
}

// in-place softmax over axis 1 (O1); one block per batch
__global__ __launch_bounds__(256) void softmax_o1(float* __restrict__ out)
{
    __shared__ float sm[2][128], ss[2][128];
    const int b  = blockIdx.x;
    const int s2 = threadIdx.x & 127;
    const int oh = threadIdx.x >> 7;
    float* p = out + (size_t)b * (O1_ * O2_) + s2;
    float m = -INFINITY, s = 0.f;
    #pragma unroll 4
    for (int o = oh * 128; o < oh * 128 + 128; ++o) {
        float v = p[(size_t)o * O2_];
        float mn = fmaxf(m, v);
        s = s * __expf(m - mn) + __expf(v - mn);
        m = mn;
    }
    sm[oh][s2] = m; ss[oh][s2] = s;
    __syncthreads();
    float M = fmaxf(sm[0][s2], sm[1][s2]);
    float S = ss[0][s2] * __expf(sm[0][s2] - M) + ss[1][s2] * __expf(sm[1][s2] - M);
    float inv = 1.f / S;
    #pragma unroll 4
    for (int o = oh * 128; o < oh * 128 + 128; ++o) {
        float v = p[(size_t)o * O2_];
        p[(size_t)o * O2_] = __expf(v - M) * inv;
    }
}

extern "C" void kernel_launch(void* const* d_in, const int* in_sizes, int n_in,
                              void* d_out, int out_size, void* d_ws, size_t ws_size,
                              hipStream_t stream)
{
    const float* x     = (const float*)d_in[0];
    const float* W1    = (const float*)d_in[1];
    const float* W     = (const float*)d_in[2];
    const float* W2    = (const float*)d_in[3];
    const float* alpha = (const float*)d_in[4];
    const float* bias  = (const float*)d_in[5];
    float* out = (float*)d_out;

    char* ws = (char*)d_ws;
    _Float16* E   = (_Float16*)ws;
    _Float16* WT  = (_Float16*)(ws + E_BYTES);
    _Float16* W2T = (_Float16*)(ws + E_BYTES + WT_BYTES);

    prep_wt<<<dim3(384), 256, 0, stream>>>(W, W2, WT, W2T);
    k1_egemm<<<dim3(2048), 256, 0, stream>>>(x, W1, E);
    k2_sy<<<dim3(1024), 256, 0, stream>>>(E, WT, W2T, alpha, bias, out);
    softmax_o1<<<B_, 256, 0, stream>>>(out);
}

// Round 13
// 143.565 us; speedup vs baseline: 1.8299x; 1.8299x over previous
//
#include <hip/hip_runtime.h>
#include <hip/hip_bf16.h>
#include <math.h>

#define B_   256
#define D1_  512
#define T_   256
#define O1_  256
#define O2_  128
#define OT   64

typedef __attribute__((ext_vector_type(8))) _Float16 f16x8;
typedef __attribute__((ext_vector_type(4))) float f32x4;

__device__ inline unsigned pkh2(float a, float b) {
    union { _Float16 h[2]; unsigned u; } c;
    c.h[0] = (_Float16)a; c.h[1] = (_Float16)b; return c.u;
}
__device__ inline uint2 cvth4(float v0, float v1, float v2, float v3) {
    uint2 r; r.x = pkh2(v0, v1); r.y = pkh2(v2, v3); return r;
}
__device__ inline f16x8 cvt8h(const float* v) {
    f16x8 r;
    #pragma unroll
    for (int j = 0; j < 8; ++j) r[j] = (_Float16)v[j];
    return r;
}
__device__ inline f16x8 ld16(const char* p) {
    union { uint2 a[2]; f16x8 v; } f;
    f.a[0] = *(const uint2*)p;
    f.a[1] = *(const uint2*)(p + 8);
    return f.v;
}
__device__ inline f16x8 ldb128(const char* p) { return *(const f16x8*)p; }

#define MFMAH __builtin_amdgcn_mfma_f32_16x16x32_f16

// OT=64 o-rows per block, 512 threads (8 waves: 2m x 4n), LDS = 71.7 KB ->
// 2 INDEPENDENT blocks/CU (the m97 multi-block overlap). fp16 hi-only
// everywhere (x-lo dropped): stage1/2/3 = 1 MFMA per fragment pair.
// Double-buffered staging, ONE barrier per K-chunk.
__global__ __launch_bounds__(512, 4) void tabl_mfma(
    const float* __restrict__ x, const float* __restrict__ W1,
    const float* __restrict__ W, const float* __restrict__ W2,
    const float* __restrict__ alpha, const float* __restrict__ bias,
    float* __restrict__ out)
{
    __shared__ __align__(16) char Eh[OT * 512];     // E / blended (fp16, XOR-swizzled)
    __shared__ __align__(16) char Bst[2][256 * 72]; // staging, hi plane only, dbuf
    __shared__ float redm[4][OT];
    __shared__ float reds[4][OT];

    const int tid    = threadIdx.x;
    const int lane16 = tid & 15;
    const int lg     = (tid >> 4) & 3;
    const int wid    = tid >> 6;        // 0..7
    const int wm     = wid >> 2;        // 0..1
    const int wn     = wid & 3;         // 0..3

    // XCD swizzle: the 4 o-tiles of a batch land on the same XCD.
    const int bid = blockIdx.x;
    const int idx = bid >> 3;
    const int b     = (bid & 7) + 8 * (idx >> 2);
    const int obase = (idx & 3) * OT;

    // staging roles
    const int xs_t  = tid & 255;        // staged row (t or s)
    const int xs_kh = tid >> 8;         // 0/1: 16 k each
    const int stO   = xs_t * 72 + xs_kh * 32;
    const int zs = tid & 127, zq = (tid >> 7) & 3;   // stage-3: 8 k each
    const int stZ   = zs * 72 + zq * 16;

    // fragment offsets
    const int rArow[2] = { obase + wm * 32 + lane16, obase + wm * 32 + 16 + lane16 };
    const int eR[2]    = { wm * 32 + lane16, wm * 32 + 16 + lane16 };
    const int eBase[2] = { eR[0] * 512, eR[1] * 512 };
    const int eSw[2]   = { (eR[0] & 7) << 4, (eR[1] & 7) << 4 };
    int bOff[4], b3Off[2];
    #pragma unroll
    for (int nt = 0; nt < 4; ++nt) bOff[nt] = (wn * 64 + nt * 16 + lane16) * 72 + lg * 16;
    #pragma unroll
    for (int nt = 0; nt < 2; ++nt) b3Off[nt] = (wn * 32 + nt * 16 + lane16) * 72 + lg * 16;

    // ================= Stage 1: E = W1h @ xh (fp16 hi-only) =================
    f32x4 Eacc[2][4];
    #pragma unroll
    for (int mt = 0; mt < 2; ++mt)
        #pragma unroll
        for (int nt = 0; nt < 4; ++nt) Eacc[mt][nt] = (f32x4){0.f,0.f,0.f,0.f};

    const float* xcol = x + (size_t)b * (D1_ * T_) + xs_t;
    float xn[16];
    f16x8 AhC[2];

    { // prologue: x chunk0 -> buf0; A chunk0 -> AhC
        float x0[16];
        #pragma unroll
        for (int j = 0; j < 16; ++j) x0[j] = xcol[(size_t)(xs_kh * 16 + j) * T_];
        #pragma unroll
        for (int mt = 0; mt < 2; ++mt) {
            float av[8];
            *(float4*)&av[0] = *(const float4*)(W1 + (size_t)rArow[mt] * D1_ + lg * 8);
            *(float4*)&av[4] = *(const float4*)(W1 + (size_t)rArow[mt] * D1_ + lg * 8 + 4);
            AhC[mt] = cvt8h(av);
        }
        #pragma unroll
        for (int q = 0; q < 4; ++q)
            *(uint2*)(Bst[0] + stO + q * 8) = cvth4(x0[q*4+0], x0[q*4+1], x0[q*4+2], x0[q*4+3]);
    }
    __syncthreads();

    #pragma unroll 2
    for (int c = 0; c < 16; ++c) {
        const int cur = c & 1;
        // issue next x loads (latency hidden under MFMA + sibling block)
        if (c < 15) {
            #pragma unroll
            for (int j = 0; j < 16; ++j)
                xn[j] = xcol[(size_t)((c + 1) * 32 + xs_kh * 16 + j) * T_];
        }
        float4 apN[2][2];
        if (c < 15) {
            #pragma unroll
            for (int mt = 0; mt < 2; ++mt) {
                const float4* ap = (const float4*)(W1 + (size_t)rArow[mt] * D1_ + (c + 1) * 32 + lg * 8);
                apN[mt][0] = ap[0]; apN[mt][1] = ap[1];
            }
        }
        // MFMA on buf[cur]
        __builtin_amdgcn_s_setprio(1);
        #pragma unroll
        for (int nt = 0; nt < 4; ++nt) {
            f16x8 Bh = ld16(Bst[cur] + bOff[nt]);
            #pragma unroll
            for (int mt = 0; mt < 2; ++mt)
                Eacc[mt][nt] = MFMAH(AhC[mt], Bh, Eacc[mt][nt], 0,0,0);
        }
        __builtin_amdgcn_s_setprio(0);
        // convert + write next chunk; convert next A
        if (c < 15) {
            #pragma unroll
            for (int q = 0; q < 4; ++q)
                *(uint2*)(Bst[cur^1] + stO + q * 8) = cvth4(xn[q*4+0], xn[q*4+1], xn[q*4+2], xn[q*4+3]);
            #pragma unroll
            for (int mt = 0; mt < 2; ++mt) {
                float av[8];
                *(float4*)&av[0] = apN[mt][0];
                *(float4*)&av[4] = apN[mt][1];
                AhC[mt] = cvt8h(av);
            }
        }
        __syncthreads();
    }

    // publish E (fp16) to LDS; Eacc dies here
    #pragma unroll
    for (int mt = 0; mt < 2; ++mt)
        #pragma unroll
        for (int nt = 0; nt < 4; ++nt)
            #pragma unroll
            for (int i = 0; i < 4; ++i) {
                int r = wm * 32 + mt * 16 + lg * 4 + i;
                int t = wn * 64 + nt * 16 + lane16;
                union { _Float16 h; unsigned short u; } cc;
                cc.h = (_Float16)Eacc[mt][nt][i];
                *(unsigned short*)(Eh + r * 512 + ((2 * t) ^ ((r & 7) << 4))) = cc.u;
            }

    // ================= Stage 2: S = Eh @ Wh  (fp16 hi-only) =================
    f32x4 Sacc[2][4];
    #pragma unroll
    for (int mt = 0; mt < 2; ++mt)
        #pragma unroll
        for (int nt = 0; nt < 4; ++nt) Sacc[mt][nt] = (f32x4){0.f,0.f,0.f,0.f};

    const float* wcol = W + xs_t;
    { // prologue: W chunk0 -> buf0
        float w0[16];
        #pragma unroll
        for (int j = 0; j < 16; ++j) w0[j] = wcol[(size_t)(xs_kh * 16 + j) * T_];
        #pragma unroll
        for (int q = 0; q < 4; ++q)
            *(uint2*)(Bst[0] + stO + q * 8) = cvth4(w0[q*4+0], w0[q*4+1], w0[q*4+2], w0[q*4+3]);
    }
    __syncthreads();   // covers E publish + W chunk0

    float wv[16];
    #pragma unroll 2
    for (int c = 0; c < 8; ++c) {
        const int cur = c & 1;
        if (c < 7) {
            #pragma unroll
            for (int j = 0; j < 16; ++j)
                wv[j] = wcol[(size_t)((c + 1) * 32 + xs_kh * 16 + j) * T_];
        }
        f16x8 Af[2];
        #pragma unroll
        for (int mt = 0; mt < 2; ++mt)
            Af[mt] = ldb128(Eh + eBase[mt] + ((c * 64 + lg * 16) ^ eSw[mt]));
        __builtin_amdgcn_s_setprio(1);
        #pragma unroll
        for (int nt = 0; nt < 4; ++nt) {
            f16x8 Bf = ld16(Bst[cur] + bOff[nt]);
            #pragma unroll
            for (int mt = 0; mt < 2; ++mt)
                Sacc[mt][nt] = MFMAH(Af[mt], Bf, Sacc[mt][nt], 0,0,0);
        }
        __builtin_amdgcn_s_setprio(0);
        if (c < 7) {
            #pragma unroll
            for (int q = 0; q < 4; ++q)
                *(uint2*)(Bst[cur^1] + stO + q * 8) = cvth4(wv[q*4+0], wv[q*4+1], wv[q*4+2], wv[q*4+3]);
        }
        __syncthreads();
    }

    // ============ row softmax over s (4 wn groups) + blend (Eh in place) ============
    const float a_ = alpha[0];
    float pm[2][4];
    #pragma unroll
    for (int mt = 0; mt < 2; ++mt)
        #pragma unroll
        for (int i = 0; i < 4; ++i) {
            float m = fmaxf(fmaxf(Sacc[mt][0][i], Sacc[mt][1][i]),
                            fmaxf(Sacc[mt][2][i], Sacc[mt][3][i]));
            m = fmaxf(m, __shfl_xor(m, 1));
            m = fmaxf(m, __shfl_xor(m, 2));
            m = fmaxf(m, __shfl_xor(m, 4));
            m = fmaxf(m, __shfl_xor(m, 8));
            float s = 0.f;
            #pragma unroll
            for (int nt = 0; nt < 4; ++nt) {
                float p = __expf(Sacc[mt][nt][i] - m);
                Sacc[mt][nt][i] = p; s += p;
            }
            s += __shfl_xor(s, 1);
            s += __shfl_xor(s, 2);
            s += __shfl_xor(s, 4);
            s += __shfl_xor(s, 8);
            pm[mt][i] = m;
            if (lane16 == 0) {
                int r = wm * 32 + mt * 16 + lg * 4 + i;
                redm[wn][r] = m; reds[wn][r] = s;
            }
        }
    __syncthreads();   // redm/reds ready; all stage-2 Eh reads done

    #pragma unroll
    for (int mt = 0; mt < 2; ++mt)
        #pragma unroll
        for (int i = 0; i < 4; ++i) {
            int r = wm * 32 + mt * 16 + lg * 4 + i;
            float M = fmaxf(fmaxf(redm[0][r], redm[1][r]),
                            fmaxf(redm[2][r], redm[3][r]));
            float den = reds[0][r] * __expf(redm[0][r] - M)
                      + reds[1][r] * __expf(redm[1][r] - M)
                      + reds[2][r] * __expf(redm[2][r] - M)
                      + reds[3][r] * __expf(redm[3][r] - M);
            float sc = __expf(pm[mt][i] - M) / den;
            #pragma unroll
            for (int nt = 0; nt < 4; ++nt) {
                float f = a_ + (1.f - a_) * Sacc[mt][nt][i] * sc;
                int t = wn * 64 + nt * 16 + lane16;
                int off = r * 512 + ((2 * t) ^ ((r & 7) << 4));
                union { _Float16 h; unsigned short u; } cc;
                cc.u = *(const unsigned short*)(Eh + off);
                cc.h = (_Float16)((float)cc.h * f);
                *(unsigned short*)(Eh + off) = cc.u;
            }
        }
    { // stage-3 prologue: W2 chunk0 -> buf0 (buf0 free after stage-2 c=6)
        float z0[8];
        #pragma unroll
        for (int j = 0; j < 8; ++j) z0[j] = W2[(size_t)(zq * 8 + j) * O2_ + zs];
        *(uint2*)(Bst[0] + stZ)     = cvth4(z0[0], z0[1], z0[2], z0[3]);
        *(uint2*)(Bst[0] + stZ + 8) = cvth4(z0[4], z0[5], z0[6], z0[7]);
    }
    __syncthreads();   // blend writes + W2 chunk0 visible

    // ========== Stage 3: Y = blended_h @ W2h + bias (fp16 hi-only) ==========
    f32x4 Yacc[2][2];
    #pragma unroll
    for (int mt = 0; mt < 2; ++mt)
        #pragma unroll
        for (int nt = 0; nt < 2; ++nt) Yacc[mt][nt] = (f32x4){0.f,0.f,0.f,0.f};

    float zv[8];
    #pragma unroll 2
    for (int c = 0; c < 8; ++c) {
        const int cur = c & 1;
        if (c < 7) {
            #pragma unroll
            for (int j = 0; j < 8; ++j)
                zv[j] = W2[(size_t)((c + 1) * 32 + zq * 8 + j) * O2_ + zs];
        }
        f16x8 Af[2];
        #pragma unroll
        for (int mt = 0; mt < 2; ++mt)
            Af[mt] = ldb128(Eh + eBase[mt] + ((c * 64 + lg * 16) ^ eSw[mt]));
        __builtin_amdgcn_s_setprio(1);
        #pragma unroll
        for (int nt = 0; nt < 2; ++nt) {
            f16x8 Bf = ld16(Bst[cur] + b3Off[nt]);
            #pragma unroll
            for (int mt = 0; mt < 2; ++mt)
                Yacc[mt][nt] = MFMAH(Af[mt], Bf, Yacc[mt][nt], 0,0,0);
        }
        __builtin_amdgcn_s_setprio(0);
        if (c < 7) {
            *(uint2*)(Bst[cur^1] + stZ)     = cvth4(zv[0], zv[1], zv[2], zv[3]);
            *(uint2*)(Bst[cur^1] + stZ + 8) = cvth4(zv[4], zv[5], zv[6], zv[7]);
        }
        __syncthreads();
    }

    // epilogue: + bias, store pre-softmax Y
    #pragma unroll
    for (int mt = 0; mt < 2; ++mt)
        #pragma unroll
        for (int nt = 0; nt < 2; ++nt)
            #pragma unroll
            for (int i = 0; i < 4; ++i) {
                int o  = obase + wm * 32 + mt * 16 + lg * 4 + i;
                int s2 = wn * 32 + nt * 16 + lane16;
                out[((size_t)b * O1_ + o) * O2_ + s2] =
                    Yacc[mt][nt][i] + bias[(size_t)o * O2_ + s2];
            }
}

// in-place softmax over axis 1 (O1); one block per batch
__global__ __launch_bounds__(256) void softmax_o1(float* __restrict__ out)
{
    __shared__ float sm[2][128], ss[2][128];
    const int b  = blockIdx.x;
    const int s2 = threadIdx.x & 127;
    const int oh = threadIdx.x >> 7;
    float* p = out + (size_t)b * (O1_ * O2_) + s2;
    float m = -INFINITY, s = 0.f;
    #pragma unroll 4
    for (int o = oh * 128; o < oh * 128 + 128; ++o) {
        float v = p[(size_t)o * O2_];
        float mn = fmaxf(m, v);
        s = s * __expf(m - mn) + __expf(v - mn);
        m = mn;
    }
    sm[oh][s2] = m; ss[oh][s2] = s;
    __syncthreads();
    float M = fmaxf(sm[0][s2], sm[1][s2]);
    float S = ss[0][s2] * __expf(sm[0][s2] - M) + ss[1][s2] * __expf(sm[1][s2] - M);
    float inv = 1.f / S;
    #pragma unroll 4
    for (int o = oh * 128; o < oh * 128 + 128; ++o) {
        float v = p[(size_t)o * O2_];
        p[(size_t)o * O2_] = __expf(v - M) * inv;
    }
}

extern "C" void kernel_launch(void* const* d_in, const int* in_sizes, int n_in,
                              void* d_out, int out_size, void* d_ws, size_t ws_size,
                              hipStream_t stream)
{
    const float* x     = (const float*)d_in[0];
    const float* W1    = (const float*)d_in[1];
    const float* W     = (const float*)d_in[2];
    const float* W2    = (const float*)d_in[3];
    const float* alpha = (const float*)d_in[4];
    const float* bias  = (const float*)d_in[5];
    float* out = (float*)d_out;

    tabl_mfma<<<dim3(1024), 512, 0, stream>>>(x, W1, W, W2, alpha, bias, out);
    softmax_o1<<<B_, 256, 0, stream>>>(out);
}